// Round 1
// baseline (216.522 us; speedup 1.0000x reference)
//
#include <hip/hip_runtime.h>

// Decorrelation (iterative whitening) normalization.
// Input:  (64, 56, 56, 256) f32, NHWC (C contiguous). N = 200704 positions.
// Groups: 16 groups x 16 channels. Newton-Schulz x5 for Sigma^{-1/2}.
//
// ws float layout:
//   [0,    256)  : channel sums (atomic accum)
//   [256,  4352) : second-moment sums per group (g*256 + i*16 + j)
//   [4352, 4608) : channel means (written by k_wm)
//   [4608, 8704) : whitening matrices (g*256 + i*16 + j)

constexpr int CCH = 256;
constexpr float EPSV = 1e-3f;

__global__ __launch_bounds__(256) void k_stats(const float* __restrict__ x,
                                               float* __restrict__ sums,
                                               float* __restrict__ covs,
                                               int npos) {
    const int tid = threadIdx.x;
    const int lane = tid & 63;
    const int wavesPerBlock = blockDim.x >> 6;
    const int wave = blockIdx.x * wavesPerBlock + (tid >> 6);
    const int nwaves = gridDim.x * wavesPerBlock;
    const int baseLane = lane & ~3;   // 4-lane cluster = 16 channels = 1 group

    float s4[4] = {0.f, 0.f, 0.f, 0.f};
    float cv[4][16];
#pragma unroll
    for (int a = 0; a < 4; ++a)
#pragma unroll
        for (int j = 0; j < 16; ++j) cv[a][j] = 0.f;

    for (int p = wave; p < npos; p += nwaves) {
        const float4 v = *reinterpret_cast<const float4*>(x + (size_t)p * CCH + lane * 4);
        s4[0] += v.x; s4[1] += v.y; s4[2] += v.z; s4[3] += v.w;
        const float va[4] = {v.x, v.y, v.z, v.w};
#pragma unroll
        for (int s = 0; s < 4; ++s) {
            float u0 = __shfl(v.x, baseLane + s, 64);
            float u1 = __shfl(v.y, baseLane + s, 64);
            float u2 = __shfl(v.z, baseLane + s, 64);
            float u3 = __shfl(v.w, baseLane + s, 64);
#pragma unroll
            for (int a = 0; a < 4; ++a) {
                cv[a][s * 4 + 0] += va[a] * u0;
                cv[a][s * 4 + 1] += va[a] * u1;
                cv[a][s * 4 + 2] += va[a] * u2;
                cv[a][s * 4 + 3] += va[a] * u3;
            }
        }
    }

    __shared__ float lsum[256];
    __shared__ float lcov[4096];
    for (int i2 = tid; i2 < 256; i2 += blockDim.x) lsum[i2] = 0.f;
    for (int i2 = tid; i2 < 4096; i2 += blockDim.x) lcov[i2] = 0.f;
    __syncthreads();

    const int g = lane >> 2;
    const int il0 = (lane & 3) * 4;
#pragma unroll
    for (int a = 0; a < 4; ++a) atomicAdd(&lsum[lane * 4 + a], s4[a]);
#pragma unroll
    for (int a = 0; a < 4; ++a)
#pragma unroll
        for (int j = 0; j < 16; ++j)
            atomicAdd(&lcov[g * 256 + (il0 + a) * 16 + j], cv[a][j]);
    __syncthreads();

    for (int i2 = tid; i2 < 256; i2 += blockDim.x) atomicAdd(&sums[i2], lsum[i2]);
    for (int i2 = tid; i2 < 4096; i2 += blockDim.x) atomicAdd(&covs[i2], lcov[i2]);
}

// One block per group; thread (i,j) owns element (i,j) of the 16x16 matrices.
__global__ __launch_bounds__(256) void k_wm(const float* __restrict__ sums,
                                            const float* __restrict__ covs,
                                            float* __restrict__ mean,
                                            float* __restrict__ wm,
                                            float inv_n) {
    const int g = blockIdx.x;
    const int tid = threadIdx.x;
    const int i = tid >> 4;
    const int j = tid & 15;

    __shared__ float mu[16];
    __shared__ float sig[16][17];
    __shared__ float P[16][17];
    __shared__ float T[16][17];
    __shared__ float U[16][17];

    if (tid < 16) {
        float m = sums[g * 16 + tid] * inv_n;
        mu[tid] = m;
        mean[g * 16 + tid] = m;
    }
    __syncthreads();

    const float cov = covs[(g * 16 + i) * 16 + j] * inv_n - mu[i] * mu[j];
    const float s = (1.0f - EPSV) * cov + ((i == j) ? EPSV : 0.0f);
    sig[i][j] = s;
    __syncthreads();

    float tr = 0.f;
#pragma unroll
    for (int k = 0; k < 16; ++k) tr += sig[k][k];
    __syncthreads();

    sig[i][j] = s / tr;               // sigma_n
    P[i][j] = (i == j) ? 1.0f : 0.0f;
    __syncthreads();

    for (int it = 0; it < 5; ++it) {
        float a = 0.f;
#pragma unroll
        for (int k = 0; k < 16; ++k) a += P[i][k] * P[k][j];
        T[i][j] = a;
        __syncthreads();

        float b = 0.f;
#pragma unroll
        for (int k = 0; k < 16; ++k) b += T[i][k] * P[k][j];
        U[i][j] = b;
        __syncthreads();

        float c = 0.f;
#pragma unroll
        for (int k = 0; k < 16; ++k) c += U[i][k] * sig[k][j];
        const float pn = 1.5f * P[i][j] - 0.5f * c;
        __syncthreads();
        P[i][j] = pn;
        __syncthreads();
    }

    wm[(g * 16 + i) * 16 + j] = P[i][j] * rsqrtf(tr);
}

__global__ __launch_bounds__(256) void k_whiten(const float* __restrict__ x,
                                                const float* __restrict__ mean,
                                                const float* __restrict__ wm,
                                                float* __restrict__ out,
                                                int npos) {
    const int tid = threadIdx.x;
    const int lane = tid & 63;
    const int wavesPerBlock = blockDim.x >> 6;
    const int wave = blockIdx.x * wavesPerBlock + (tid >> 6);
    const int nwaves = gridDim.x * wavesPerBlock;
    const int g = lane >> 2;
    const int i0 = (lane & 3) * 4;
    const int baseLane = lane & ~3;

    // Per-lane whitening rows: 4 output channels x 16 input channels.
    float w[4][16];
    const float* wg = wm + g * 256;
#pragma unroll
    for (int a = 0; a < 4; ++a)
#pragma unroll
        for (int j = 0; j < 16; ++j) w[a][j] = wg[(i0 + a) * 16 + j];

    const float4 mu4 = *reinterpret_cast<const float4*>(mean + lane * 4);

    for (int p = wave; p < npos; p += nwaves) {
        float4 v = *reinterpret_cast<const float4*>(x + (size_t)p * CCH + lane * 4);
        v.x -= mu4.x; v.y -= mu4.y; v.z -= mu4.z; v.w -= mu4.w;
        float acc[4] = {0.f, 0.f, 0.f, 0.f};
#pragma unroll
        for (int s = 0; s < 4; ++s) {
            float u0 = __shfl(v.x, baseLane + s, 64);
            float u1 = __shfl(v.y, baseLane + s, 64);
            float u2 = __shfl(v.z, baseLane + s, 64);
            float u3 = __shfl(v.w, baseLane + s, 64);
#pragma unroll
            for (int a = 0; a < 4; ++a) {
                acc[a] += w[a][4 * s + 0] * u0 + w[a][4 * s + 1] * u1 +
                          w[a][4 * s + 2] * u2 + w[a][4 * s + 3] * u3;
            }
        }
        float4 o;
        o.x = acc[0]; o.y = acc[1]; o.z = acc[2]; o.w = acc[3];
        *reinterpret_cast<float4*>(out + (size_t)p * CCH + lane * 4) = o;
    }
}

extern "C" void kernel_launch(void* const* d_in, const int* in_sizes, int n_in,
                              void* d_out, int out_size, void* d_ws, size_t ws_size,
                              hipStream_t stream) {
    const float* x = (const float*)d_in[0];
    float* out = (float*)d_out;
    float* ws = (float*)d_ws;

    const int total = in_sizes[0];
    const int npos = total / CCH;   // 200704
    const float inv_n = 1.0f / (float)npos;

    // zero the accumulator region (sums + cov sums)
    hipMemsetAsync(d_ws, 0, 4352 * sizeof(float), stream);

    k_stats<<<512, 256, 0, stream>>>(x, ws, ws + 256, npos);
    k_wm<<<16, 256, 0, stream>>>(ws, ws + 256, ws + 4352, ws + 4608, inv_n);
    k_whiten<<<2048, 256, 0, stream>>>(x, ws + 4352, ws + 4608, out, npos);
}